// Round 19
// baseline (2582.839 us; speedup 1.0000x reference)
//
#include <hip/hip_runtime.h>

// GridCellRouter: N=4096*4096 cells, 16 iterations of
//   accum[idx[i]] += cur[i];  cur[i] = accum[i] - cur[i]
//
// Recurrence (verified R4): c_{t+1} = S c_t + c_{t-1}, answer = c16 + c15.
// BSGS (verified R8): answer = sum_{k=0..16} alpha_k S^k r,
//   alpha = [1,8,36,84,210,252,462,330,495,220,286,78,91,14,15,1,1].
//   3 applies of S + 4 applies of T=S^4 (Horner, w_q fused into acc epilogue).
// R14 (verified, 2579 us): two-level radix route (32-stream scatters are
//   line-compact; route1/route2 each < ~90 us) broke the ~320 us/pass
//   random-line invariant for the apply path.
//
// R15: composes (2 x 318, top items; transaction-bound at 3.5 TB/s with zero
// L3 reuse) cannot be made cheaper serially. Instead HIDE them: compose
// slices ride as TAIL JOBS on the baby-apply kernels (compact streaming
// passes stress BW; compose stresses the random-transaction pipe).
//   F1 = route1(S,r)  + c1/3   F4 = route1(S,B1) + c2/3
//   F2 = route2       + c1/3   F5 = route2       + c2/3
//   F3 = acc->B1      + c1/3   F6 = acc->B2      + c2/3
//   F7 = route1(S,B2) + b1(T)-tail ; then T scans; F8 route2; F9 acc->B3
// Tail blocks: uniform per-block branch (b >= mainGrid), no barrier mixing.
// Falsifier: total ~= 2580 => transaction ceiling is shared => roofline.
// ALL indices masked -> no OOB anywhere.
// (R22 resubmit: R15/R19/R20/R21 never ran — GPU broker timeouts.)

#define N_CELLS (1 << 24)

#define BKT_BITS 14
#define NBKT (N_CELLS >> BKT_BITS)        // 1024 final buckets
#define DPB (1 << BKT_BITS)               // 16384 dsts per bucket
#define BKT_MASK (DPB - 1)
#define IDX_MASK (N_CELLS - 1)
#define NSUP 32                           // super buckets (dst >> 19)
#define SUP_SHIFT 19
#define G1 256                            // b1/route1/route2 main wgs
#define BT 1024                           // threads in b1/route1/route2
#define EPW (N_CELLS / G1)                // 65536 edges per wg

// compose slice sizes (elements): A,B on 1024-thr kernels (4096/blk),
// C on 512-thr acc (2048/blk). A+B+C = N exactly.
#define CSA_BLK 1638
#define CSA_ELEMS (CSA_BLK * 4096)        // 6709248
#define CSC_BLK 1640                      // (N - 2*CSA_ELEMS) / 2048

typedef unsigned uv4 __attribute__((ext_vector_type(4)));
typedef float fv4 __attribute__((ext_vector_type(4)));
typedef unsigned long long u64;

__device__ __align__(16) unsigned g_T[2][NBKT * G1];      // b1 counts (bucket, wg)
__device__ __align__(16) unsigned g_bktcnt[2][NBKT];      // bucket totals
__device__ __align__(16) unsigned g_S[2][NBKT + 4];       // bucket starts (excl)
__device__ __align__(16) unsigned g_off1[2][NSUP * G1];   // route1 cursors (super, wg)
__device__ __align__(16) unsigned g_off2[2][NBKT * 8];    // route2 cursors (bucket, group)
__device__ __align__(16) uint2 g_tmp[N_CELLS];            // pass-1 records (val, dst24)
__device__ __align__(16) uint2 g_rec[N_CELLS];            // final records (val, dst)
__device__ __align__(16) int g_idx2[N_CELLS];             // idx o idx
__device__ __align__(16) int g_idx4[N_CELLS];             // idx2 o idx2
__device__ __align__(16) float gB1[N_CELLS];              // S r
__device__ __align__(16) float gB2[N_CELLS];              // S^2 r
__device__ __align__(16) float gB3[N_CELLS];              // S^3 r
__device__ __align__(16) float gH[N_CELLS];               // Horner ping buffer

// pointer selector (host can't take addresses of __device__ statics)
__device__ __forceinline__ float* sel_buf(int which, const float* r, float* dout) {
    switch (which) {
        case 0: return (float*)r;
        case 1: return gB1;
        case 2: return gB2;
        case 3: return gB3;
        case 4: return gH;
        default: return dout;
    }
}

// ---- tail jobs ----

// compose slice: o[i] = a[a[i]] for elems [base + tb*nthr*4, +nthr*4)
__device__ __forceinline__ void dev_cmp(const int* __restrict__ ext, int mode,
                                        unsigned base, unsigned tb, int t, int nthr) {
    const int* __restrict__ a = mode ? g_idx2 : ext;
    int* __restrict__ o = mode ? g_idx4 : g_idx2;
    size_t i = (size_t)base + ((size_t)tb * nthr + (unsigned)t) * 4u;
    int4 v = *reinterpret_cast<const int4*>(a + i);
    int4 r;
    r.x = a[v.x & IDX_MASK];
    r.y = a[v.y & IDX_MASK];
    r.z = a[v.z & IDX_MASK];
    r.w = a[v.w & IDX_MASK];
    *reinterpret_cast<int4*>(o + i) = r;
}

// b1(T) workgroup: count idx4 edges per (bucket, wg-chunk). 1024 thr, 4KB LDS.
__device__ __forceinline__ void dev_b1T(unsigned* h, unsigned wg, int t) {
    h[t] = 0u;
    __syncthreads();
    const uv4* p = reinterpret_cast<const uv4*>(g_idx4) + (size_t)wg * (EPW / 4);
    for (int k = 0; k < EPW / 4 / BT; ++k) {   // 16 iters
        uv4 v = __builtin_nontemporal_load(&p[k * BT + t]);
        atomicAdd(&h[(v.x & IDX_MASK) >> BKT_BITS], 1u);
        atomicAdd(&h[(v.y & IDX_MASK) >> BKT_BITS], 1u);
        atomicAdd(&h[(v.z & IDX_MASK) >> BKT_BITS], 1u);
        atomicAdd(&h[(v.w & IDX_MASK) >> BKT_BITS], 1u);
    }
    __syncthreads();
    g_T[1][(size_t)t * G1 + wg] = h[t];
}

// ---- build kernels ----

// b1: count edges per (final bucket, wg) for set 0 (external idx)
__global__ void __launch_bounds__(BT) b1_count(const int* __restrict__ ext) {
    __shared__ unsigned h[NBKT];
    int t = threadIdx.x;
    h[t] = 0u;
    __syncthreads();
    const uv4* p = reinterpret_cast<const uv4*>(ext) + (size_t)blockIdx.x * (EPW / 4);
    for (int k = 0; k < EPW / 4 / BT; ++k) {   // 16 iters
        uv4 v = __builtin_nontemporal_load(&p[k * BT + t]);
        atomicAdd(&h[(v.x & IDX_MASK) >> BKT_BITS], 1u);
        atomicAdd(&h[(v.y & IDX_MASK) >> BKT_BITS], 1u);
        atomicAdd(&h[(v.z & IDX_MASK) >> BKT_BITS], 1u);
        atomicAdd(&h[(v.w & IDX_MASK) >> BKT_BITS], 1u);
    }
    __syncthreads();
    g_T[0][(size_t)t * G1 + blockIdx.x] = h[t];
}

// s1: bucket totals (row of G1=256 contiguous)
__global__ void s1_sums(int set) {
    __shared__ unsigned sd[256];
    int t = threadIdx.x;
    sd[t] = g_T[set][(size_t)blockIdx.x * G1 + t];
    __syncthreads();
    for (int off = 128; off > 0; off >>= 1) {
        if (t < off) sd[t] += sd[t + off];
        __syncthreads();
    }
    if (t == 0) g_bktcnt[set][blockIdx.x] = sd[0];
}

// s2: exclusive scan of g_bktcnt[1024] -> g_S (proven pattern; sums to N)
__global__ void s2_scan(int set) {
    __shared__ unsigned s[256];
    int t = threadIdx.x;
    uint4 v = reinterpret_cast<const uint4*>(g_bktcnt[set])[t];
    unsigned local = v.x + v.y + v.z + v.w;
    s[t] = local;
    __syncthreads();
    for (int off = 1; off < 256; off <<= 1) {
        unsigned add = (t >= off) ? s[t - off] : 0u;
        __syncthreads();
        s[t] += add;
        __syncthreads();
    }
    unsigned run = s[t] - local;
    uint4 o;
    o.x = run; run += v.x;
    o.y = run; run += v.y;
    o.z = run; run += v.z;
    o.w = run;
    reinterpret_cast<uint4*>(g_S[set])[t] = o;
    if (t == 0) g_S[set][NBKT] = (unsigned)N_CELLS;
}

// d_off1: route1 cursor bases. off1[s][w] = g_S[s*32] +
//   excl-prefix_w( sum_{b in super s} g_T[b][w] ). Grid: NSUP wgs x 256 thr.
__global__ void d_off1(int set) {
    __shared__ unsigned sc[G1];
    int w = threadIdx.x;
    unsigned s = blockIdx.x;
    unsigned c = 0u;
    for (int j = 0; j < NBKT / NSUP; ++j)   // 32 buckets per super
        c += g_T[set][(size_t)(s * (NBKT / NSUP) + j) * G1 + w];
    sc[w] = c;
    __syncthreads();
    for (int off = 1; off < G1; off <<= 1) {
        unsigned add = (w >= off) ? sc[w - off] : 0u;
        __syncthreads();
        sc[w] += add;
        __syncthreads();
    }
    g_off1[set][(size_t)s * G1 + w] = g_S[set][s * (NBKT / NSUP)] + sc[w] - c;
}

// d_off2: route2 cursor bases. off2[b][g] = g_S[b] +
//   sum_{g'<g} ( sum_{w in group g'} g_T[b][w] ). Grid: NBKT wgs x 256 thr.
__global__ void d_off2(int set) {
    __shared__ unsigned sd[256];
    int t = threadIdx.x;
    unsigned b = blockIdx.x;
    sd[t] = g_T[set][(size_t)b * G1 + t];
    __syncthreads();
    for (int off = 16; off > 0; off >>= 1) {   // reduce within each group of 32
        if ((t & 31) < off) sd[t] += sd[t + off];
        __syncthreads();
    }
    if (t == 0) {
        unsigned run = g_S[set][b];
        for (int g = 0; g < 8; ++g) {
            g_off2[set][(size_t)b * 8 + g] = run;
            run += sd[g * 32];
        }
    }
}

// ---- apply kernels (R14-verified mains + tail-job branch) ----

// route1: seq read idx+ct chunk; scatter (val, dst24) via 32 LDS cursors
// into super-bucket-major g_tmp. tailk: 0 none, 1 c1-slice, 2 c2-slice, 3 b1T.
__global__ void __launch_bounds__(BT) route1(const float* __restrict__ rin,
                                             float* __restrict__ dout,
                                             const int* __restrict__ ext,
                                             int ct_sel, int set,
                                             int tailk, unsigned tail_base) {
    __shared__ unsigned sh[NBKT];   // main uses [0,32); b1T tail uses all
    unsigned b = blockIdx.x;
    int t = threadIdx.x;
    if (b >= (unsigned)G1) {
        unsigned tb = b - G1;
        if (tailk == 1) dev_cmp(ext, 0, tail_base, tb, t, BT);
        else if (tailk == 2) dev_cmp(ext, 1, tail_base, tb, t, BT);
        else if (tailk == 3) dev_b1T(sh, tb, t);
        return;
    }
    const int* __restrict__ idx = set ? g_idx4 : ext;
    const float* __restrict__ ct = sel_buf(ct_sel, rin, dout);
    if (t < NSUP) sh[t] = g_off1[set][(size_t)t * G1 + b];
    __syncthreads();
    const uv4* ip = reinterpret_cast<const uv4*>(idx) + (size_t)b * (EPW / 4);
    const fv4* cp = reinterpret_cast<const fv4*>(ct) + (size_t)b * (EPW / 4);
    for (int k = 0; k < EPW / 4 / BT; ++k) {   // 16 iters
        uv4 v = __builtin_nontemporal_load(&ip[k * BT + t]);
        fv4 c = __builtin_nontemporal_load(&cp[k * BT + t]);
        unsigned e, p;
        e = v.x & IDX_MASK; p = atomicAdd(&sh[e >> SUP_SHIFT], 1u) & IDX_MASK;
        g_tmp[p] = make_uint2(__float_as_uint(c.x), e);
        e = v.y & IDX_MASK; p = atomicAdd(&sh[e >> SUP_SHIFT], 1u) & IDX_MASK;
        g_tmp[p] = make_uint2(__float_as_uint(c.y), e);
        e = v.z & IDX_MASK; p = atomicAdd(&sh[e >> SUP_SHIFT], 1u) & IDX_MASK;
        g_tmp[p] = make_uint2(__float_as_uint(c.z), e);
        e = v.w & IDX_MASK; p = atomicAdd(&sh[e >> SUP_SHIFT], 1u) & IDX_MASK;
        g_tmp[p] = make_uint2(__float_as_uint(c.w), e);
    }
}

// route2: wg = (super s, group g of 32 wg1s). Seq read of the group's FULL
// runs in g_tmp; scatter via 32 sub-bucket cursors into final-bucket g_rec.
__global__ void __launch_bounds__(BT) route2(int set, const int* __restrict__ ext,
                                             int tailk, unsigned tail_base) {
    __shared__ unsigned cur[NSUP];
    unsigned wg = blockIdx.x;
    int t = threadIdx.x;
    if (wg >= (unsigned)G1) {
        unsigned tb = wg - G1;
        if (tailk == 1) dev_cmp(ext, 0, tail_base, tb, t, BT);
        else if (tailk == 2) dev_cmp(ext, 1, tail_base, tb, t, BT);
        return;
    }
    unsigned s = wg >> 3, g = wg & 7u;
    if (t < NSUP) cur[t] = g_off2[set][(size_t)(s * NSUP + t) * 8 + g];
    __syncthreads();
    unsigned start = g_off1[set][(size_t)s * G1 + g * 32];
    unsigned end = (g < 7u) ? g_off1[set][(size_t)s * G1 + (g + 1) * 32]
                            : g_S[set][(s + 1) * NSUP];
    if (start > end) start = end;
    const u64* __restrict__ tmp = reinterpret_cast<const u64*>(g_tmp);
    unsigned e = start + t;
    for (; e + 3 * BT < end; e += 4 * BT) {
        u64 q0 = __builtin_nontemporal_load(&tmp[e]);
        u64 q1 = __builtin_nontemporal_load(&tmp[e + BT]);
        u64 q2 = __builtin_nontemporal_load(&tmp[e + 2 * BT]);
        u64 q3 = __builtin_nontemporal_load(&tmp[e + 3 * BT]);
        unsigned d0 = (unsigned)(q0 >> 32), d1 = (unsigned)(q1 >> 32);
        unsigned d2 = (unsigned)(q2 >> 32), d3 = (unsigned)(q3 >> 32);
        unsigned p0 = atomicAdd(&cur[(d0 >> BKT_BITS) & 31u], 1u) & IDX_MASK;
        unsigned p1 = atomicAdd(&cur[(d1 >> BKT_BITS) & 31u], 1u) & IDX_MASK;
        unsigned p2 = atomicAdd(&cur[(d2 >> BKT_BITS) & 31u], 1u) & IDX_MASK;
        unsigned p3 = atomicAdd(&cur[(d3 >> BKT_BITS) & 31u], 1u) & IDX_MASK;
        g_rec[p0] = make_uint2((unsigned)q0, d0);
        g_rec[p1] = make_uint2((unsigned)q1, d1);
        g_rec[p2] = make_uint2((unsigned)q2, d2);
        g_rec[p3] = make_uint2((unsigned)q3, d3);
    }
    for (; e < end; e += BT) {
        u64 q = __builtin_nontemporal_load(&tmp[e]);
        unsigned d = (unsigned)(q >> 32);
        unsigned p = atomicAdd(&cur[(d >> BKT_BITS) & 31u], 1u) & IDX_MASK;
        g_rec[p] = make_uint2((unsigned)q, d);
    }
}

// acc: sequential record read; LDS float-atomic acc over 16384 dsts;
// epilogue: out[row] = acc[row] + (fuse ? a0*r + a1*B1 + a2*B2 + a3*B3 : 0)
__global__ void __launch_bounds__(512) acc_op(const float* __restrict__ rin,
                                              float* __restrict__ dout,
                                              int out_sel, int set, int fuse,
                                              float a0, float a1, float a2, float a3,
                                              const int* __restrict__ ext,
                                              int tailk, unsigned tail_base) {
    __shared__ float acc[DPB];   // 64 KB
    int t = threadIdx.x;
    unsigned b = blockIdx.x;
    if (b >= (unsigned)NBKT) {
        unsigned tb = b - NBKT;
        if (tailk == 1) dev_cmp(ext, 0, tail_base, tb, t, 512);
        else if (tailk == 2) dev_cmp(ext, 1, tail_base, tb, t, 512);
        return;
    }
    float* __restrict__ out = sel_buf(out_sel, rin, dout);
    unsigned base = g_S[set][b];
    unsigned end = g_S[set][b + 1];
    if (end > (unsigned)N_CELLS) end = (unsigned)N_CELLS;
    if (base > end) base = end;
    fv4* acc4 = reinterpret_cast<fv4*>(acc);
    fv4 z = (fv4)(0.0f);
    for (int k = 0; k < DPB / 4 / 512; ++k) acc4[k * 512 + t] = z;   // 8 iters
    __syncthreads();
    const u64* __restrict__ rec = reinterpret_cast<const u64*>(g_rec);
    unsigned e = base + t;
    for (; e + 1536 < end; e += 2048) {
        u64 q0 = __builtin_nontemporal_load(&rec[e]);
        u64 q1 = __builtin_nontemporal_load(&rec[e + 512]);
        u64 q2 = __builtin_nontemporal_load(&rec[e + 1024]);
        u64 q3 = __builtin_nontemporal_load(&rec[e + 1536]);
        atomicAdd(&acc[(unsigned)(q0 >> 32) & BKT_MASK], __uint_as_float((unsigned)q0));
        atomicAdd(&acc[(unsigned)(q1 >> 32) & BKT_MASK], __uint_as_float((unsigned)q1));
        atomicAdd(&acc[(unsigned)(q2 >> 32) & BKT_MASK], __uint_as_float((unsigned)q2));
        atomicAdd(&acc[(unsigned)(q3 >> 32) & BKT_MASK], __uint_as_float((unsigned)q3));
    }
    for (; e < end; e += 512) {
        u64 q = __builtin_nontemporal_load(&rec[e]);
        atomicAdd(&acc[(unsigned)(q >> 32) & BKT_MASK], __uint_as_float((unsigned)q));
    }
    __syncthreads();
    size_t rowbase = (size_t)b * (DPB / 4);
    fv4* out4 = reinterpret_cast<fv4*>(out) + rowbase;
    if (fuse) {
        const fv4* r4 = reinterpret_cast<const fv4*>(rin) + rowbase;
        const fv4* p1 = reinterpret_cast<const fv4*>(gB1) + rowbase;
        const fv4* p2 = reinterpret_cast<const fv4*>(gB2) + rowbase;
        const fv4* p3 = reinterpret_cast<const fv4*>(gB3) + rowbase;
        for (int k = 0; k < DPB / 4 / 512; ++k) {
            int j = k * 512 + t;
            fv4 a = acc4[j];
            fv4 x = __builtin_nontemporal_load(&r4[j]);
            fv4 y = __builtin_nontemporal_load(&p1[j]);
            fv4 u = __builtin_nontemporal_load(&p2[j]);
            fv4 w = __builtin_nontemporal_load(&p3[j]);
            a += a0 * x + a1 * y + a2 * u + a3 * w;
            __builtin_nontemporal_store(a, &out4[j]);
        }
    } else {
        for (int k = 0; k < DPB / 4 / 512; ++k) {
            int j = k * 512 + t;
            __builtin_nontemporal_store(acc4[j], &out4[j]);
        }
    }
}

extern "C" void kernel_launch(void* const* d_in, const int* in_sizes, int n_in,
                              void* d_out, int out_size, void* d_ws, size_t ws_size,
                              hipStream_t stream) {
    const int* idx = (const int*)d_in[1];
    const float* r = (const float*)d_in[0];   // read-only
    float* out = (float*)d_out;
    const unsigned csB = CSA_ELEMS;           // slice B base
    const unsigned csC = 2u * CSA_ELEMS;      // slice C base

    // ---- build S layout (set 0) ----
    b1_count<<<G1, BT, 0, stream>>>(idx);
    s1_sums<<<NBKT, 256, 0, stream>>>(0);
    s2_scan<<<1, 256, 0, stream>>>(0);
    d_off1<<<NSUP, G1, 0, stream>>>(0);
    d_off2<<<NBKT, 256, 0, stream>>>(0);

    // ---- babies with compose / b1(T) tail jobs ----
    // F1..F3: apply S to r (-> B1)  ||  compose1 (idx2 = idx o idx)
    route1<<<G1 + CSA_BLK, BT, 0, stream>>>(r, out, idx, 0, 0, 1, 0u);
    route2<<<G1 + CSA_BLK, BT, 0, stream>>>(0, idx, 1, csB);
    acc_op<<<NBKT + CSC_BLK, 512, 0, stream>>>(r, out, 1, 0, 0, 0.f, 0.f, 0.f, 0.f,
                                               idx, 1, csC);
    // F4..F6: apply S to B1 (-> B2)  ||  compose2 (idx4 = idx2 o idx2)
    route1<<<G1 + CSA_BLK, BT, 0, stream>>>(r, out, idx, 1, 0, 2, 0u);
    route2<<<G1 + CSA_BLK, BT, 0, stream>>>(0, idx, 2, csB);
    acc_op<<<NBKT + CSC_BLK, 512, 0, stream>>>(r, out, 2, 0, 0, 0.f, 0.f, 0.f, 0.f,
                                               idx, 2, csC);
    // F7: route1(S, B2)  ||  b1(T) tail (256 wgs)
    route1<<<G1 + G1, BT, 0, stream>>>(r, out, idx, 2, 0, 3, 0u);
    // T scans (tiny)
    s1_sums<<<NBKT, 256, 0, stream>>>(1);
    s2_scan<<<1, 256, 0, stream>>>(1);
    d_off1<<<NSUP, G1, 0, stream>>>(1);
    d_off2<<<NBKT, 256, 0, stream>>>(1);
    // F8, F9: finish B3
    route2<<<G1, BT, 0, stream>>>(0, idx, 0, 0u);
    acc_op<<<NBKT, 512, 0, stream>>>(r, out, 3, 0, 0, 0.f, 0.f, 0.f, 0.f, idx, 0, 0u);

    // ---- giant steps: Horner over T = S^4 ----
    // alpha (k=0..16): 1,8,36,84,210,252,462,330,495,220,286,78,91,14,15,1,1
    // g3 = T r  + w3 : (91,14,15,1)      -> gH
    route1<<<G1, BT, 0, stream>>>(r, out, idx, 0, 1, 0, 0u);
    route2<<<G1, BT, 0, stream>>>(1, idx, 0, 0u);
    acc_op<<<NBKT, 512, 0, stream>>>(r, out, 4, 1, 1, 91.f, 14.f, 15.f, 1.f, idx, 0, 0u);
    // g2 = T g3 + w2 : (495,220,286,78)  -> d_out
    route1<<<G1, BT, 0, stream>>>(r, out, idx, 4, 1, 0, 0u);
    route2<<<G1, BT, 0, stream>>>(1, idx, 0, 0u);
    acc_op<<<NBKT, 512, 0, stream>>>(r, out, 5, 1, 1, 495.f, 220.f, 286.f, 78.f, idx, 0, 0u);
    // g1 = T g2 + w1 : (210,252,462,330) -> gH
    route1<<<G1, BT, 0, stream>>>(r, out, idx, 5, 1, 0, 0u);
    route2<<<G1, BT, 0, stream>>>(1, idx, 0, 0u);
    acc_op<<<NBKT, 512, 0, stream>>>(r, out, 4, 1, 1, 210.f, 252.f, 462.f, 330.f, idx, 0, 0u);
    // g0 = T g1 + w0 : (1,8,36,84)       -> d_out  (= answer)
    route1<<<G1, BT, 0, stream>>>(r, out, idx, 4, 1, 0, 0u);
    route2<<<G1, BT, 0, stream>>>(1, idx, 0, 0u);
    acc_op<<<NBKT, 512, 0, stream>>>(r, out, 5, 1, 1, 1.f, 8.f, 36.f, 84.f, idx, 0, 0u);
}